// Round 26
// baseline (126.334 us; speedup 1.0000x reference)
//
#include <hip/hip_runtime.h>
#include <math.h>

#define D_MODEL 768
#define NHEADS  12
#define HDIM    64
#define SEQ     1024
#define BATCH   8
#define NBH     (BATCH*NHEADS)          // 96
#define M_TOTAL (BATCH*SEQ)             // 8192
#define KT_D    (D_MODEL/32)            // 24
#define QKV_COLS (3*D_MODEL)            // 2304

typedef __attribute__((ext_vector_type(8))) short bf16x8;
typedef __attribute__((ext_vector_type(4))) float f32x4;

#define MFMA16(a,b,c) __builtin_amdgcn_mfma_f32_16x16x32_bf16((a),(b),(c),0,0,0)

// Q pre-scale: 1/sqrt(64) * log2(e) so softmax runs in exp2 domain
#define QSCALE 0.18033688011112042f

// ---- helpers ----------------------------------------------------------------
__device__ inline unsigned short f2bf(float f) {
    unsigned u = __float_as_uint(f);
    u += 0x7FFFu + ((u >> 16) & 1u);
    return (unsigned short)(u >> 16);
}
__device__ inline void gload16(const void* g, const void* l) {
    __builtin_amdgcn_global_load_lds(
        (const __attribute__((address_space(1))) unsigned*)g,
        (__attribute__((address_space(3))) unsigned*)l, 16, 0, 0);
}
__device__ inline float exp2_fast(float x) {
#if __has_builtin(__builtin_amdgcn_exp2f)
    return __builtin_amdgcn_exp2f(x);
#else
    float r; asm("v_exp_f32 %0, %1" : "=v"(r) : "v"(x)); return r;
#endif
}

// Fragment containers: ALL operands hi-only bf16 (512 ushorts per 16x32 subtile;
// A-frag: lane=(row%16)+((k%32)/8)*16, slot=k%8; B-frag identical with row->col).

#define NA_TOT 786432      // x -> Xf (hi-only A frags)
#define NB1_TOT 221184     // w_qkv -> Wq (hi-only B frags)
#define NB2_TOT 73728      // w_proj -> Wp (hi-only B frags)

// ---- fused converts: one launch, three gid segments --------------------------
__global__ __launch_bounds__(256)
void convert_all(const float* __restrict__ x,    unsigned short* __restrict__ Xf,
                 const float* __restrict__ wq,   unsigned short* __restrict__ Wq,
                 const float* __restrict__ wp,   unsigned short* __restrict__ Wp)
{
    const int gid = blockIdx.x * 256 + threadIdx.x;
    const int lane = gid & 63;
    if (gid < NA_TOT) {
        // x (fp32 [M][K]) -> A-fragments, HI-ONLY
        const int sub = gid >> 6;
        const int kt = sub % KT_D;
        const int mt = sub / KT_D;
        const float* s = x + (size_t)(mt*16 + (lane & 15)) * D_MODEL + kt*32 + (lane >> 4)*8;
        float4 v0 = *(const float4*)(s);
        float4 v1 = *(const float4*)(s + 4);
        float vv[8] = {v0.x, v0.y, v0.z, v0.w, v1.x, v1.y, v1.z, v1.w};
        union { unsigned short u[8]; bf16x8 v; } H;
        #pragma unroll
        for (int i = 0; i < 8; ++i) H.u[i] = f2bf(vv[i]);
        *(bf16x8*)(Xf + (size_t)sub * 512 + lane * 8) = H.v;
    } else {
        // weights (fp32 [K][N]) -> B-fragments, HI-ONLY
        const float* src;
        unsigned short* dst;
        int sub, ldN;
        if (gid < NA_TOT + NB1_TOT) {
            src = wq; dst = Wq; ldN = QKV_COLS; sub = (gid - NA_TOT) >> 6;
        } else if (gid < NA_TOT + NB1_TOT + NB2_TOT) {
            src = wp; dst = Wp; ldN = D_MODEL; sub = (gid - NA_TOT - NB1_TOT) >> 6;
        } else {
            return;
        }
        const int kt = sub % KT_D;
        const int nt = sub / KT_D;
        const int n  = nt*16 + (lane & 15);
        const int k0 = kt*32 + (lane >> 4)*8;
        const float* s = src + (size_t)k0 * ldN + n;
        union { unsigned short u[8]; bf16x8 v; } H;
        #pragma unroll
        for (int i = 0; i < 8; ++i) H.u[i] = f2bf(s[(size_t)i * ldN]);
        *(bf16x8*)(dst + (size_t)sub * 512 + lane * 8) = H.v;
    }
}

// ---- fragment GEMM, pure bf16, 3-buffer 1-barrier counted-vmcnt pipeline -----
// 3-unrolled steady loop: every LDS buffer index compile-time. Schedule per kt:
// [vmcnt(CPW) — kt's chunks landed (issued 2 iters ago); s_barrier; stage kt+2;
// ds_read buf kt%3; setprio(1) MFMA setprio(0)].
// MODE 0: 8 waves (2x4), 128x128 tile, 48KB LDS; scatters Q/K/V hi-only frags.
// MODE 1: 4 waves (2x2), 128x64 tile, 36KB LDS; fp32 out + bias.
// 1-D grid, XCD swizzle: mb=(bid&7)*8+((bid>>3)&7), nb=bid>>6.
template<int MODE>
__global__ __launch_bounds__(MODE == 0 ? 512 : 256, 4)
void gemm_frag(const unsigned short* __restrict__ Af,
               const unsigned short* __restrict__ Bf,
               const float* __restrict__ bias,
               float* __restrict__ outF,
               unsigned short* __restrict__ outQ,
               unsigned short* __restrict__ outK,
               unsigned short* __restrict__ outV)
{
    constexpr int NW     = (MODE == 0) ? 8 : 4;     // waves per block
    constexpr int NSUB_N = (MODE == 0) ? 8 : 4;     // B subtiles per block
    constexpr int ACH    = 8;                       // A hi 1KB-chunks per kt
    constexpr int NCH    = ACH + NSUB_N;            // chunks per kt (16 / 12)
    constexpr int CPW    = NCH / NW;                // chunks per wave (2 / 3)
    __shared__ unsigned short sm[3][NCH * 512];
    const int t = threadIdx.x, lane = t & 63, wid = t >> 6;
    const int wr = (MODE == 0) ? (wid >> 2) : (wid >> 1);
    const int wc = (MODE == 0) ? (wid & 3)  : (wid & 1);
    const int bid = blockIdx.x;
    const int mb = (bid & 7) * 8 + ((bid >> 3) & 7);
    const int nb = bid >> 6;

    f32x4 acc[4][2] = {};

    // stage K-step ktv into buffer Lb (CPW chunks per wave)
    auto stageTo = [&](unsigned short* Lb, int ktv) {
        #pragma unroll
        for (int i = 0; i < CPW; ++i) {
            const int c = wid * CPW + i;
            const unsigned short* g;
            if (c < ACH) {                     // A hi subtile c
                g = Af + ((size_t)(mb*8 + c)*KT_D + ktv)*512 + lane*8;
            } else {                           // B hi subtile j
                const int j = c - ACH;
                g = Bf + ((size_t)(nb*NSUB_N + j)*KT_D + ktv)*512 + lane*8;
            }
            gload16(g, (const char*)Lb + (size_t)c*1024);
        }
    };
    auto waitCPW = [&] {
        if (MODE == 0) asm volatile("s_waitcnt vmcnt(2)" ::: "memory");
        else           asm volatile("s_waitcnt vmcnt(3)" ::: "memory");
    };
    auto compute = [&](const unsigned short* Lb) {
        bf16x8 bh[2];
        #pragma unroll
        for (int n = 0; n < 2; ++n)
            bh[n] = *(const bf16x8*)(Lb + (ACH + wc*2 + n)*512 + lane*8);
        bf16x8 ah[4];
        #pragma unroll
        for (int m = 0; m < 4; ++m)
            ah[m] = *(const bf16x8*)(Lb + (wr*4 + m)*512 + lane*8);
        __builtin_amdgcn_s_setprio(1);
        #pragma unroll
        for (int m = 0; m < 4; ++m)
            #pragma unroll
            for (int n = 0; n < 2; ++n)
                acc[m][n] = MFMA16(ah[m], bh[n], acc[m][n]);
        __builtin_amdgcn_s_setprio(0);
    };

    stageTo(&sm[0][0], 0);
    stageTo(&sm[1][0], 1);

    // steady: buffer indices compile-time; KT_D%3==0
    for (int ktb = 0; ktb < KT_D - 3; ktb += 3) {
        waitCPW(); __builtin_amdgcn_s_barrier();
        stageTo(&sm[2][0], ktb + 2);  compute(&sm[0][0]);
        waitCPW(); __builtin_amdgcn_s_barrier();
        stageTo(&sm[0][0], ktb + 3);  compute(&sm[1][0]);
        waitCPW(); __builtin_amdgcn_s_barrier();
        stageTo(&sm[1][0], ktb + 4);  compute(&sm[2][0]);
    }
    // tail: kt = KT_D-3 (stages KT_D-1), KT_D-2, KT_D-1 (bufs 0,1,2)
    waitCPW(); __builtin_amdgcn_s_barrier();
    stageTo(&sm[2][0], KT_D - 1);  compute(&sm[0][0]);
    waitCPW(); __builtin_amdgcn_s_barrier();
    compute(&sm[1][0]);
    asm volatile("s_waitcnt vmcnt(0)" ::: "memory");
    __builtin_amdgcn_s_barrier();
    compute(&sm[2][0]);

    const int rowW = mb*128 + wr*64;
    const int colW = nb*(NSUB_N*16) + wc*32;
    if (MODE == 1) {
        #pragma unroll
        for (int m = 0; m < 4; ++m)
            #pragma unroll
            for (int n = 0; n < 2; ++n) {
                const int col = colW + n*16 + (lane & 15);
                const float bv = bias[col];
                #pragma unroll
                for (int r = 0; r < 4; ++r) {
                    const int row = rowW + m*16 + (lane >> 4)*4 + r;
                    outF[(size_t)row * D_MODEL + col] = acc[m][n][r] + bv;
                }
            }
    } else {
        // wave-uniform (which, head): colW..colW+31 stays inside one head (64-wide)
        const int which = colW / D_MODEL;
        const int h     = (colW % D_MODEL) >> 6;
        #pragma unroll
        for (int m = 0; m < 4; ++m)
            #pragma unroll
            for (int n = 0; n < 2; ++n) {
                const int col = colW + n*16 + (lane & 15);
                const int d = col & 63;
                const float bv = bias[col];
                #pragma unroll
                for (int r = 0; r < 4; ++r) {
                    const int row = rowW + m*16 + (lane >> 4)*4 + r;
                    const int b = row >> 10, sq = row & 1023;
                    float val = acc[m][n][r] + bv;
                    if (which <= 1) {                    // Q (scaled) / K: hi-only A-frag
                        if (which == 0) val *= QSCALE;
                        const int sub = (sq >> 4)*2 + (d >> 5);
                        const int lp  = (sq & 15) + (((d & 31) >> 3) << 4);
                        unsigned short* dst = (which == 0) ? outQ : outK;
                        dst[(size_t)(b*NHEADS + h)*65536
                            + (size_t)sub*512 + lp*8 + (d & 7)] = f2bf(val);
                    } else {                             // V: hi-only B-frag
                        const int sub = (d >> 4)*32 + (sq >> 5);
                        const int lp  = (d & 15) + (((sq & 31) >> 3) << 4);
                        outV[(size_t)(b*NHEADS + h)*65536
                             + (size_t)sub*512 + lp*8 + (sq & 7)] = f2bf(val);
                    }
                }
            }
    }
}

// ---- flash attention: 8 waves x 16 q-rows, swapped QK^T, V DIRECT FROM L2 ----
// V is L2-resident (128KB/head, XCD swizzle pins all 8 q-blocks of a head to
// one XCD) -> Vsm staging was pure overhead (Common-mistake #7). V fragments
// now load per-wave global->reg at phase start; QK^T + softmax (~300+ cyc)
// cover the ~200-cyc L2 latency. LDS reads/wave-jt 18->10; K staging is now
// branch-free (1 gload16/wave); LDS 48->32KB.
// Swapped QK^T (S^T = K x Q): P row-local -> 4 ds_write_b64/jt, scalar m/alpha,
// 2-shuffle row-reduce. dbuf K staging; Q,K,V hi-only; PV hi-only; MFMA-ones
// rowsum (trunc-P); defer-max THR=8; exp2 domain; setprio clusters. 24 waves/CU.
__global__ __launch_bounds__(512, 6)
void attn_frag(const unsigned short* __restrict__ Qf,
               const unsigned short* __restrict__ Kf,
               const unsigned short* __restrict__ Vf,
               unsigned short* __restrict__ Cf)
{
    __shared__ unsigned short Ksm[2][8 * 512];   // dbuf: 4 jn x 2 kt hi subtiles
    __shared__ unsigned short Psm[8 * 1024];     // per-wave P: 2 subtiles x 512 bf16

    const int t = threadIdx.x, lane = t & 63, wid = t >> 6;   // wid 0..7
    // XCD swizzle: all 8 q-blocks of one (b,h) land on the same XCD
    const int bid = blockIdx.x;
    const int qb  = (bid >> 3) & 7;
    const int bh  = (bid & 7) * 12 + (bid >> 6);
    const int mt0 = qb*8 + wid;                // wave's q-subtile (of 64)
    const size_t kBase = (size_t)bh * 65536;   // Q/K/V all 65536-stride

    const int qrow0 = (lane >> 4) * 4;         // 0,4,8,12
    const int slot0 = ((lane >> 4) & 1) * 4;   // 0/4: k-slot base for P store

    // stage K hi subtiles of kv-tile jt into buffer b (1 chunk per wave)
    auto stage = [&](int b, int jt) {
        const unsigned short* gk = Kf + kBase + (size_t)(jt*8 + wid)*512;
        gload16(gk + lane*8, (const char*)&Ksm[b][0] + (size_t)wid*1024);
    };

    stage(0, 0);                               // prologue: tile 0 into buf 0

    // Q hi fragments in registers (already scaled by QSCALE); overlap prologue.
    bf16x8 qh[2];
    #pragma unroll
    for (int kt = 0; kt < 2; ++kt)
        qh[kt] = *(const bf16x8*)(Qf + kBase + ((size_t)mt0*2 + kt)*512 + lane*8);

    // per-lane V base (B-frag layout: sub = dt*32 + (jt*2+kt2))
    const unsigned short* Vg = Vf + kBase + lane*8;

    // ones B-frag for the MFMA rowsum
    bf16x8 ones;
    #pragma unroll
    for (int i = 0; i < 8; ++i) ones[i] = (short)0x3F80;

    f32x4 out[4] = {};
    f32x4 lacc = {};
    float m_run = -INFINITY;                   // scalar: this thread's q row

    unsigned short* Pw = Psm + wid * 1024;

    __syncthreads();                           // prologue stage complete

    for (int jt = 0; jt < 16; ++jt) {
        const int cur = jt & 1;
        if (jt + 1 < 16) stage(cur ^ 1, jt + 1);   // prefetch next K tile (hidden)

        // issue V fragment loads (L2) early — consumed after softmax
        bf16x8 vreg[8];
        #pragma unroll
        for (int dt = 0; dt < 4; ++dt)
            #pragma unroll
            for (int kt2 = 0; kt2 < 2; ++kt2)
                vreg[dt*2 + kt2] = *(const bf16x8*)(Vg + (size_t)(dt*32 + jt*2 + kt2)*512);

        // S^T = K Q (swapped): s[jn][r] = S[q=lane&15][k=16*jn+qrow0+r]
        f32x4 s[4] = {};
        __builtin_amdgcn_s_setprio(1);
        #pragma unroll
        for (int jn = 0; jn < 4; ++jn)
            #pragma unroll
            for (int kt = 0; kt < 2; ++kt) {
                const bf16x8 kh = *(const bf16x8*)(&Ksm[cur][0] + (jn*2 + kt)*512 + lane*8);
                s[jn] = MFMA16(kh, qh[kt], s[jn]);
            }
        __builtin_amdgcn_s_setprio(0);

        // defer-max: in-lane max over this q's 16 k-values
        float mymax = s[0][0];
        #pragma unroll
        for (int jn = 0; jn < 4; ++jn)
            #pragma unroll
            for (int r = 0; r < 4; ++r)
                mymax = fmaxf(mymax, s[jn][r]);
        if (!__all(mymax <= m_run + 8.0f)) {
            float v = mymax;
            v = fmaxf(v, __shfl_xor(v, 16));
            v = fmaxf(v, __shfl_xor(v, 32));
            const float mn = fmaxf(m_run, v);
            const float al = exp2_fast(m_run - mn);
            m_run = mn;
            #pragma unroll
            for (int r = 0; r < 4; ++r) {
                const float alf = __shfl(al, qrow0 + r);   // alpha of out-row q'
                #pragma unroll
                for (int dt = 0; dt < 4; ++dt)
                    out[dt][r] *= alf;
                lacc[r] *= alf;
            }
        }

        // P = exp2(s - m): 4 consecutive k per jn -> pack + ds_write_b64
        #pragma unroll
        for (int jn = 0; jn < 4; ++jn) {
            const unsigned b0 = __float_as_uint(exp2_fast(s[jn][0] - m_run));
            const unsigned b1 = __float_as_uint(exp2_fast(s[jn][1] - m_run));
            const unsigned b2 = __float_as_uint(exp2_fast(s[jn][2] - m_run));
            const unsigned b3 = __float_as_uint(exp2_fast(s[jn][3] - m_run));
            const unsigned u0 = (b0 >> 16) | (b1 & 0xFFFF0000u);
            const unsigned u1 = (b2 >> 16) | (b3 & 0xFFFF0000u);
            const int hi2 = ((jn & 1) << 1) + (lane >> 5);
            const int lp  = (lane & 15) + (hi2 << 4);
            const int idx = (((lp << 3) | slot0) ^ (lp & 0x18));
            *(uint2*)&Pw[(jn >> 1)*512 + idx] = make_uint2(u0, u1);
        }

        // PV + MFMA rowsum: P from wave-local LDS, V from registers
        const int rdswz = (lane*8) ^ (lane & 0x18);
        __builtin_amdgcn_s_setprio(1);
        #pragma unroll
        for (int kt2 = 0; kt2 < 2; ++kt2) {
            const bf16x8 pa = *(const bf16x8*)(Pw + kt2*512 + rdswz);
            #pragma unroll
            for (int dt = 0; dt < 4; ++dt)
                out[dt] = MFMA16(pa, vreg[dt*2 + kt2], out[dt]);
            lacc = MFMA16(pa, ones, lacc);
        }
        __builtin_amdgcn_s_setprio(0);

        __syncthreads();   // next K tile staged by ALL waves; this tile's reads done
    }

    // epilogue: ctx / l -> proj-GEMM A-fragments, HI-ONLY
    const int b = bh / NHEADS, h = bh % NHEADS;
    #pragma unroll
    for (int r = 0; r < 4; ++r) {
        const float inv = 1.0f / lacc[r];
        const int sq = mt0*16 + qrow0 + r;
        const int mrow = b*SEQ + sq;
        #pragma unroll
        for (int dt = 0; dt < 4; ++dt) {
            const int c = h*64 + dt*16 + (lane & 15);
            const float val = out[dt][r] * inv;
            Cf[((size_t)(mrow >> 4)*KT_D + (c >> 5))*512
               + ((mrow & 15) + (((c & 31) >> 3) << 4))*8 + (c & 7)] = f2bf(val);
        }
    }
}

// ---------------------------------------------------------------------------
extern "C" void kernel_launch(void* const* d_in, const int* in_sizes, int n_in,
                              void* d_out, int out_size, void* d_ws, size_t ws_size,
                              hipStream_t stream)
{
    const float* x      = (const float*)d_in[0];
    const float* w_qkv  = (const float*)d_in[1];
    const float* b_qkv  = (const float*)d_in[2];
    const float* w_proj = (const float*)d_in[3];
    const float* b_proj = (const float*)d_in[4];
    float* out = (float*)d_out;

    unsigned short* ws = (unsigned short*)d_ws;
    unsigned short* Xf = ws;                    // 12288 sub * 512    =  6,291,456
    unsigned short* Wq = Xf + 6291456;          // 3456 sub * 512     =  1,769,472
    unsigned short* Wp = Wq + 1769472;          // 1152 sub * 512     =    589,824
    unsigned short* Qf = Wp + 589824;           // 96 * 65536         =  6,291,456
    unsigned short* Kf = Qf + 6291456;          // 96 * 65536         =  6,291,456
    unsigned short* Vf = Kf + 6291456;          // 96 * 65536         =  6,291,456
    unsigned short* Cf = Vf + 6291456;          // 12288 sub * 512    =  6,291,456
    // total ~33.8M ushorts = ~64 MB of d_ws

    // fused converts: (786432 + 221184 + 73728) threads = 4224 blocks
    convert_all<<<dim3(4224), 256, 0, stream>>>(x, Xf, w_qkv, Wq, w_proj, Wp);

    // gemm0: 128x128 tiles -> grid 64 x 18 = 1152 (mb-swizzled, nb = bid>>6)
    gemm_frag<0><<<dim3(1152), 512, 0, stream>>>(Xf, Wq, b_qkv, nullptr, Qf, Kf, Vf);
    attn_frag<<<dim3(768), 512, 0, stream>>>(Qf, Kf, Vf, Cf);
    // gemm1: 128x64 tiles -> grid 64 x 12 = 768
    gemm_frag<1><<<dim3(768), 256, 0, stream>>>(Cf, Wp, b_proj, out,
                                                nullptr, nullptr, nullptr);
}

// Round 27
// 106.708 us; speedup vs baseline: 1.1839x; 1.1839x over previous
//
#include <hip/hip_runtime.h>
#include <math.h>

#define D_MODEL 768
#define NHEADS  12
#define HDIM    64
#define SEQ     1024
#define BATCH   8
#define NBH     (BATCH*NHEADS)          // 96
#define M_TOTAL (BATCH*SEQ)             // 8192
#define KT_D    (D_MODEL/32)            // 24
#define QKV_COLS (3*D_MODEL)            // 2304

typedef __attribute__((ext_vector_type(8))) short bf16x8;
typedef __attribute__((ext_vector_type(4))) float f32x4;

#define MFMA16(a,b,c) __builtin_amdgcn_mfma_f32_16x16x32_bf16((a),(b),(c),0,0,0)

// Q pre-scale: 1/sqrt(64) * log2(e) so softmax runs in exp2 domain
#define QSCALE 0.18033688011112042f

// ---- helpers ----------------------------------------------------------------
__device__ inline unsigned short f2bf(float f) {
    unsigned u = __float_as_uint(f);
    u += 0x7FFFu + ((u >> 16) & 1u);
    return (unsigned short)(u >> 16);
}
__device__ inline void gload16(const void* g, const void* l) {
    __builtin_amdgcn_global_load_lds(
        (const __attribute__((address_space(1))) unsigned*)g,
        (__attribute__((address_space(3))) unsigned*)l, 16, 0, 0);
}
__device__ inline float exp2_fast(float x) {
#if __has_builtin(__builtin_amdgcn_exp2f)
    return __builtin_amdgcn_exp2f(x);
#else
    float r; asm("v_exp_f32 %0, %1" : "=v"(r) : "v"(x)); return r;
#endif
}

// Fragment containers: ALL operands hi-only bf16 (512 ushorts per 16x32 subtile;
// A-frag: lane=(row%16)+((k%32)/8)*16, slot=k%8; B-frag identical with row->col).

#define NA_TOT 786432      // x -> Xf (hi-only A frags)
#define NB1_TOT 221184     // w_qkv -> Wq (hi-only B frags)
#define NB2_TOT 73728      // w_proj -> Wp (hi-only B frags)

// ---- fused converts: one launch, three gid segments --------------------------
__global__ __launch_bounds__(256)
void convert_all(const float* __restrict__ x,    unsigned short* __restrict__ Xf,
                 const float* __restrict__ wq,   unsigned short* __restrict__ Wq,
                 const float* __restrict__ wp,   unsigned short* __restrict__ Wp)
{
    const int gid = blockIdx.x * 256 + threadIdx.x;
    const int lane = gid & 63;
    if (gid < NA_TOT) {
        // x (fp32 [M][K]) -> A-fragments, HI-ONLY
        const int sub = gid >> 6;
        const int kt = sub % KT_D;
        const int mt = sub / KT_D;
        const float* s = x + (size_t)(mt*16 + (lane & 15)) * D_MODEL + kt*32 + (lane >> 4)*8;
        float4 v0 = *(const float4*)(s);
        float4 v1 = *(const float4*)(s + 4);
        float vv[8] = {v0.x, v0.y, v0.z, v0.w, v1.x, v1.y, v1.z, v1.w};
        union { unsigned short u[8]; bf16x8 v; } H;
        #pragma unroll
        for (int i = 0; i < 8; ++i) H.u[i] = f2bf(vv[i]);
        *(bf16x8*)(Xf + (size_t)sub * 512 + lane * 8) = H.v;
    } else {
        // weights (fp32 [K][N]) -> B-fragments, HI-ONLY
        const float* src;
        unsigned short* dst;
        int sub, ldN;
        if (gid < NA_TOT + NB1_TOT) {
            src = wq; dst = Wq; ldN = QKV_COLS; sub = (gid - NA_TOT) >> 6;
        } else if (gid < NA_TOT + NB1_TOT + NB2_TOT) {
            src = wp; dst = Wp; ldN = D_MODEL; sub = (gid - NA_TOT - NB1_TOT) >> 6;
        } else {
            return;
        }
        const int kt = sub % KT_D;
        const int nt = sub / KT_D;
        const int n  = nt*16 + (lane & 15);
        const int k0 = kt*32 + (lane >> 4)*8;
        const float* s = src + (size_t)k0 * ldN + n;
        union { unsigned short u[8]; bf16x8 v; } H;
        #pragma unroll
        for (int i = 0; i < 8; ++i) H.u[i] = f2bf(s[(size_t)i * ldN]);
        *(bf16x8*)(dst + (size_t)sub * 512 + lane * 8) = H.v;
    }
}

// ---- fragment GEMM, pure bf16, 3-buffer 1-barrier counted-vmcnt pipeline -----
// 3-unrolled steady loop: every LDS buffer index compile-time. Schedule per kt:
// [vmcnt(CPW) — kt's chunks landed (issued 2 iters ago); s_barrier; stage kt+2;
// ds_read buf kt%3; setprio(1) MFMA setprio(0)].
// MODE 0: 8 waves (2x4), 128x128 tile, 48KB LDS; scatters Q/K/V hi-only frags.
// MODE 1: 4 waves (2x2), 128x64 tile, 36KB LDS; fp32 out + bias.
// 1-D grid, XCD swizzle: mb=(bid&7)*8+((bid>>3)&7), nb=bid>>6.
template<int MODE>
__global__ __launch_bounds__(MODE == 0 ? 512 : 256, 4)
void gemm_frag(const unsigned short* __restrict__ Af,
               const unsigned short* __restrict__ Bf,
               const float* __restrict__ bias,
               float* __restrict__ outF,
               unsigned short* __restrict__ outQ,
               unsigned short* __restrict__ outK,
               unsigned short* __restrict__ outV)
{
    constexpr int NW     = (MODE == 0) ? 8 : 4;     // waves per block
    constexpr int NSUB_N = (MODE == 0) ? 8 : 4;     // B subtiles per block
    constexpr int ACH    = 8;                       // A hi 1KB-chunks per kt
    constexpr int NCH    = ACH + NSUB_N;            // chunks per kt (16 / 12)
    constexpr int CPW    = NCH / NW;                // chunks per wave (2 / 3)
    __shared__ unsigned short sm[3][NCH * 512];
    const int t = threadIdx.x, lane = t & 63, wid = t >> 6;
    const int wr = (MODE == 0) ? (wid >> 2) : (wid >> 1);
    const int wc = (MODE == 0) ? (wid & 3)  : (wid & 1);
    const int bid = blockIdx.x;
    const int mb = (bid & 7) * 8 + ((bid >> 3) & 7);
    const int nb = bid >> 6;

    f32x4 acc[4][2] = {};

    // stage K-step ktv into buffer Lb (CPW chunks per wave)
    auto stageTo = [&](unsigned short* Lb, int ktv) {
        #pragma unroll
        for (int i = 0; i < CPW; ++i) {
            const int c = wid * CPW + i;
            const unsigned short* g;
            if (c < ACH) {                     // A hi subtile c
                g = Af + ((size_t)(mb*8 + c)*KT_D + ktv)*512 + lane*8;
            } else {                           // B hi subtile j
                const int j = c - ACH;
                g = Bf + ((size_t)(nb*NSUB_N + j)*KT_D + ktv)*512 + lane*8;
            }
            gload16(g, (const char*)Lb + (size_t)c*1024);
        }
    };
    auto waitCPW = [&] {
        if (MODE == 0) asm volatile("s_waitcnt vmcnt(2)" ::: "memory");
        else           asm volatile("s_waitcnt vmcnt(3)" ::: "memory");
    };
    auto compute = [&](const unsigned short* Lb) {
        bf16x8 bh[2];
        #pragma unroll
        for (int n = 0; n < 2; ++n)
            bh[n] = *(const bf16x8*)(Lb + (ACH + wc*2 + n)*512 + lane*8);
        bf16x8 ah[4];
        #pragma unroll
        for (int m = 0; m < 4; ++m)
            ah[m] = *(const bf16x8*)(Lb + (wr*4 + m)*512 + lane*8);
        __builtin_amdgcn_s_setprio(1);
        #pragma unroll
        for (int m = 0; m < 4; ++m)
            #pragma unroll
            for (int n = 0; n < 2; ++n)
                acc[m][n] = MFMA16(ah[m], bh[n], acc[m][n]);
        __builtin_amdgcn_s_setprio(0);
    };

    stageTo(&sm[0][0], 0);
    stageTo(&sm[1][0], 1);

    // steady: buffer indices compile-time; KT_D%3==0
    for (int ktb = 0; ktb < KT_D - 3; ktb += 3) {
        waitCPW(); __builtin_amdgcn_s_barrier();
        stageTo(&sm[2][0], ktb + 2);  compute(&sm[0][0]);
        waitCPW(); __builtin_amdgcn_s_barrier();
        stageTo(&sm[0][0], ktb + 3);  compute(&sm[1][0]);
        waitCPW(); __builtin_amdgcn_s_barrier();
        stageTo(&sm[1][0], ktb + 4);  compute(&sm[2][0]);
    }
    // tail: kt = KT_D-3 (stages KT_D-1), KT_D-2, KT_D-1 (bufs 0,1,2)
    waitCPW(); __builtin_amdgcn_s_barrier();
    stageTo(&sm[2][0], KT_D - 1);  compute(&sm[0][0]);
    waitCPW(); __builtin_amdgcn_s_barrier();
    compute(&sm[1][0]);
    asm volatile("s_waitcnt vmcnt(0)" ::: "memory");
    __builtin_amdgcn_s_barrier();
    compute(&sm[2][0]);

    const int rowW = mb*128 + wr*64;
    const int colW = nb*(NSUB_N*16) + wc*32;
    if (MODE == 1) {
        #pragma unroll
        for (int m = 0; m < 4; ++m)
            #pragma unroll
            for (int n = 0; n < 2; ++n) {
                const int col = colW + n*16 + (lane & 15);
                const float bv = bias[col];
                #pragma unroll
                for (int r = 0; r < 4; ++r) {
                    const int row = rowW + m*16 + (lane >> 4)*4 + r;
                    outF[(size_t)row * D_MODEL + col] = acc[m][n][r] + bv;
                }
            }
    } else {
        // wave-uniform (which, head): colW..colW+31 stays inside one head (64-wide)
        const int which = colW / D_MODEL;
        const int h     = (colW % D_MODEL) >> 6;
        #pragma unroll
        for (int m = 0; m < 4; ++m)
            #pragma unroll
            for (int n = 0; n < 2; ++n) {
                const int col = colW + n*16 + (lane & 15);
                const int d = col & 63;
                const float bv = bias[col];
                #pragma unroll
                for (int r = 0; r < 4; ++r) {
                    const int row = rowW + m*16 + (lane >> 4)*4 + r;
                    const int b = row >> 10, sq = row & 1023;
                    float val = acc[m][n][r] + bv;
                    if (which <= 1) {                    // Q (scaled) / K: hi-only A-frag
                        if (which == 0) val *= QSCALE;
                        const int sub = (sq >> 4)*2 + (d >> 5);
                        const int lp  = (sq & 15) + (((d & 31) >> 3) << 4);
                        unsigned short* dst = (which == 0) ? outQ : outK;
                        dst[(size_t)(b*NHEADS + h)*65536
                            + (size_t)sub*512 + lp*8 + (d & 7)] = f2bf(val);
                    } else {                             // V: hi-only B-frag
                        const int sub = (d >> 4)*32 + (sq >> 5);
                        const int lp  = (d & 15) + (((sq & 31) >> 3) << 4);
                        outV[(size_t)(b*NHEADS + h)*65536
                             + (size_t)sub*512 + lp*8 + (sq & 7)] = f2bf(val);
                    }
                }
            }
    }
}

// ---- flash attention: 8 waves x 16 q-rows, SWAPPED QK^T (S^T = K x Q) --------
// R25 CONFIG RESTORED (best measured, 107.4us e2e). R26's V-direct-from-L2
// regressed 45->69us: compiler sank the V loads to their MFMA use points
// (VGPR stayed 40 — vreg never held live), exposing serial L2 latency in PV.
// Swapped operands put P row-local: thread owns q = lane&15 and k = 16*jn +
// qrow0 + r — 4 consecutive k per jn -> P store is 4 ds_write_b64/jt, scalar
// m/alpha, 2-shuffle row reduce. dbuf K/V staging; Q,K,V hi-only; PV hi-only;
// MFMA-ones rowsum (trunc-P); defer-max THR=8; exp2 domain; setprio clusters.
__global__ __launch_bounds__(512, 6)
void attn_frag(const unsigned short* __restrict__ Qf,
               const unsigned short* __restrict__ Kf,
               const unsigned short* __restrict__ Vf,
               unsigned short* __restrict__ Cf)
{
    __shared__ unsigned short Ksm[2][8 * 512];   // dbuf: 4 jn x 2 kt hi subtiles
    __shared__ unsigned short Vsm[2][8 * 512];   // dbuf: 4 dt x 2 kt2 hi subtiles
    __shared__ unsigned short Psm[8 * 1024];     // per-wave P: 2 subtiles x 512 bf16

    const int t = threadIdx.x, lane = t & 63, wid = t >> 6;   // wid 0..7
    // XCD swizzle: all 8 q-blocks of one (b,h) land on the same XCD
    const int bid = blockIdx.x;
    const int qb  = (bid >> 3) & 7;
    const int bh  = (bid & 7) * 12 + (bid >> 6);
    const int mt0 = qb*8 + wid;                // wave's q-subtile (of 64)
    const size_t kBase = (size_t)bh * 65536;   // Q/K/V all 65536-stride

    const int qrow0 = (lane >> 4) * 4;         // 0,4,8,12
    const int slot0 = ((lane >> 4) & 1) * 4;   // 0/4: k-slot base for P store

    // stage K/V hi subtiles of kv-tile jt into buffer b (2 chunks per wave)
    auto stage = [&](int b, int jt) {
        #pragma unroll
        for (int i = 0; i < 2; ++i) {
            const int ch = wid*2 + i;
            if (ch < 8) {
                const unsigned short* gk = Kf + kBase + (size_t)(jt*8 + ch)*512;
                gload16(gk + lane*8, (const char*)&Ksm[b][0] + (size_t)ch*1024);
            } else {
                const int cv = ch - 8;                 // dt = cv>>1, kt2 = cv&1
                const unsigned short* gv = Vf + kBase
                    + (size_t)((cv >> 1)*32 + jt*2 + (cv & 1))*512;
                gload16(gv + lane*8, (const char*)&Vsm[b][0] + (size_t)cv*1024);
            }
        }
    };

    stage(0, 0);                               // prologue: tile 0 into buf 0

    // Q hi fragments in registers (already scaled by QSCALE); overlap prologue.
    bf16x8 qh[2];
    #pragma unroll
    for (int kt = 0; kt < 2; ++kt)
        qh[kt] = *(const bf16x8*)(Qf + kBase + ((size_t)mt0*2 + kt)*512 + lane*8);

    // ones B-frag for the MFMA rowsum
    bf16x8 ones;
    #pragma unroll
    for (int i = 0; i < 8; ++i) ones[i] = (short)0x3F80;

    f32x4 out[4] = {};
    f32x4 lacc = {};
    float m_run = -INFINITY;                   // scalar: this thread's q row

    unsigned short* Pw = Psm + wid * 1024;

    __syncthreads();                           // prologue stage complete

    for (int jt = 0; jt < 16; ++jt) {
        const int cur = jt & 1;
        if (jt + 1 < 16) stage(cur ^ 1, jt + 1);   // prefetch next tile (hidden)

        // S^T = K Q (swapped): s[jn][r] = S[q=lane&15][k=16*jn+qrow0+r]
        f32x4 s[4] = {};
        __builtin_amdgcn_s_setprio(1);
        #pragma unroll
        for (int jn = 0; jn < 4; ++jn)
            #pragma unroll
            for (int kt = 0; kt < 2; ++kt) {
                const bf16x8 kh = *(const bf16x8*)(&Ksm[cur][0] + (jn*2 + kt)*512 + lane*8);
                s[jn] = MFMA16(kh, qh[kt], s[jn]);
            }
        __builtin_amdgcn_s_setprio(0);

        // defer-max: in-lane max over this q's 16 k-values
        float mymax = s[0][0];
        #pragma unroll
        for (int jn = 0; jn < 4; ++jn)
            #pragma unroll
            for (int r = 0; r < 4; ++r)
                mymax = fmaxf(mymax, s[jn][r]);
        if (!__all(mymax <= m_run + 8.0f)) {
            float v = mymax;
            v = fmaxf(v, __shfl_xor(v, 16));
            v = fmaxf(v, __shfl_xor(v, 32));
            const float mn = fmaxf(m_run, v);
            const float al = exp2_fast(m_run - mn);
            m_run = mn;
            #pragma unroll
            for (int r = 0; r < 4; ++r) {
                const float alf = __shfl(al, qrow0 + r);   // alpha of out-row q'
                #pragma unroll
                for (int dt = 0; dt < 4; ++dt)
                    out[dt][r] *= alf;
                lacc[r] *= alf;
            }
        }

        // P = exp2(s - m): 4 consecutive k per jn -> pack + ds_write_b64
        #pragma unroll
        for (int jn = 0; jn < 4; ++jn) {
            const unsigned b0 = __float_as_uint(exp2_fast(s[jn][0] - m_run));
            const unsigned b1 = __float_as_uint(exp2_fast(s[jn][1] - m_run));
            const unsigned b2 = __float_as_uint(exp2_fast(s[jn][2] - m_run));
            const unsigned b3 = __float_as_uint(exp2_fast(s[jn][3] - m_run));
            const unsigned u0 = (b0 >> 16) | (b1 & 0xFFFF0000u);
            const unsigned u1 = (b2 >> 16) | (b3 & 0xFFFF0000u);
            const int hi2 = ((jn & 1) << 1) + (lane >> 5);
            const int lp  = (lane & 15) + (hi2 << 4);
            const int idx = (((lp << 3) | slot0) ^ (lp & 0x18));
            *(uint2*)&Pw[(jn >> 1)*512 + idx] = make_uint2(u0, u1);
        }

        // PV + MFMA rowsum: read P back as bf16x8 A-frags (wave-local)
        const int rdswz = (lane*8) ^ (lane & 0x18);
        __builtin_amdgcn_s_setprio(1);
        #pragma unroll
        for (int kt2 = 0; kt2 < 2; ++kt2) {
            const bf16x8 pa = *(const bf16x8*)(Pw + kt2*512 + rdswz);
            #pragma unroll
            for (int dt = 0; dt < 4; ++dt) {
                const bf16x8 vh = *(const bf16x8*)(&Vsm[cur][0] + (dt*2 + kt2)*512 + lane*8);
                out[dt] = MFMA16(pa, vh, out[dt]);
            }
            lacc = MFMA16(pa, ones, lacc);
        }
        __builtin_amdgcn_s_setprio(0);

        __syncthreads();   // next tile staged by ALL waves; this tile's reads done
    }

    // epilogue: ctx / l -> proj-GEMM A-fragments, HI-ONLY
    const int b = bh / NHEADS, h = bh % NHEADS;
    #pragma unroll
    for (int r = 0; r < 4; ++r) {
        const float inv = 1.0f / lacc[r];
        const int sq = mt0*16 + qrow0 + r;
        const int mrow = b*SEQ + sq;
        #pragma unroll
        for (int dt = 0; dt < 4; ++dt) {
            const int c = h*64 + dt*16 + (lane & 15);
            const float val = out[dt][r] * inv;
            Cf[((size_t)(mrow >> 4)*KT_D + (c >> 5))*512
               + ((mrow & 15) + (((c & 31) >> 3) << 4))*8 + (c & 7)] = f2bf(val);
        }
    }
}

// ---------------------------------------------------------------------------
extern "C" void kernel_launch(void* const* d_in, const int* in_sizes, int n_in,
                              void* d_out, int out_size, void* d_ws, size_t ws_size,
                              hipStream_t stream)
{
    const float* x      = (const float*)d_in[0];
    const float* w_qkv  = (const float*)d_in[1];
    const float* b_qkv  = (const float*)d_in[2];
    const float* w_proj = (const float*)d_in[3];
    const float* b_proj = (const float*)d_in[4];
    float* out = (float*)d_out;

    unsigned short* ws = (unsigned short*)d_ws;
    unsigned short* Xf = ws;                    // 12288 sub * 512    =  6,291,456
    unsigned short* Wq = Xf + 6291456;          // 3456 sub * 512     =  1,769,472
    unsigned short* Wp = Wq + 1769472;          // 1152 sub * 512     =    589,824
    unsigned short* Qf = Wp + 589824;           // 96 * 65536         =  6,291,456
    unsigned short* Kf = Qf + 6291456;          // 96 * 65536         =  6,291,456
    unsigned short* Vf = Kf + 6291456;          // 96 * 65536         =  6,291,456
    unsigned short* Cf = Vf + 6291456;          // 12288 sub * 512    =  6,291,456
    // total ~33.8M ushorts = ~64 MB of d_ws

    // fused converts: (786432 + 221184 + 73728) threads = 4224 blocks
    convert_all<<<dim3(4224), 256, 0, stream>>>(x, Xf, w_qkv, Wq, w_proj, Wp);

    // gemm0: 128x128 tiles -> grid 64 x 18 = 1152 (mb-swizzled, nb = bid>>6)
    gemm_frag<0><<<dim3(1152), 512, 0, stream>>>(Xf, Wq, b_qkv, nullptr, Qf, Kf, Vf);
    attn_frag<<<dim3(768), 512, 0, stream>>>(Qf, Kf, Vf, Cf);
    // gemm1: 128x64 tiles -> grid 64 x 12 = 768
    gemm_frag<1><<<dim3(768), 256, 0, stream>>>(Cf, Wp, b_proj, out,
                                                nullptr, nullptr, nullptr);
}

// Round 28
// 106.090 us; speedup vs baseline: 1.1908x; 1.0058x over previous
//
#include <hip/hip_runtime.h>
#include <math.h>

#define D_MODEL 768
#define NHEADS  12
#define HDIM    64
#define SEQ     1024
#define BATCH   8
#define NBH     (BATCH*NHEADS)          // 96
#define M_TOTAL (BATCH*SEQ)             // 8192
#define KT_D    (D_MODEL/32)            // 24
#define QKV_COLS (3*D_MODEL)            // 2304

typedef __attribute__((ext_vector_type(8))) short bf16x8;
typedef __attribute__((ext_vector_type(4))) float f32x4;

#define MFMA16(a,b,c) __builtin_amdgcn_mfma_f32_16x16x32_bf16((a),(b),(c),0,0,0)

// Q pre-scale: 1/sqrt(64) * log2(e) so softmax runs in exp2 domain
#define QSCALE 0.18033688011112042f

// ---- helpers ----------------------------------------------------------------
__device__ inline unsigned short f2bf(float f) {
    unsigned u = __float_as_uint(f);
    u += 0x7FFFu + ((u >> 16) & 1u);
    return (unsigned short)(u >> 16);
}
__device__ inline void gload16(const void* g, const void* l) {
    __builtin_amdgcn_global_load_lds(
        (const __attribute__((address_space(1))) unsigned*)g,
        (__attribute__((address_space(3))) unsigned*)l, 16, 0, 0);
}
__device__ inline float exp2_fast(float x) {
#if __has_builtin(__builtin_amdgcn_exp2f)
    return __builtin_amdgcn_exp2f(x);
#else
    float r; asm("v_exp_f32 %0, %1" : "=v"(r) : "v"(x)); return r;
#endif
}

// Fragment containers: ALL operands hi-only bf16 (512 ushorts per 16x32 subtile;
// A-frag: lane=(row%16)+((k%32)/8)*16, slot=k%8; B-frag identical with row->col).

#define NA_TOT 786432      // x -> Xf (hi-only A frags)
#define NB1_TOT 221184     // w_qkv -> Wq (hi-only B frags)
#define NB2_TOT 73728      // w_proj -> Wp (hi-only B frags)

// ---- fused converts: one launch, three gid segments --------------------------
__global__ __launch_bounds__(256)
void convert_all(const float* __restrict__ x,    unsigned short* __restrict__ Xf,
                 const float* __restrict__ wq,   unsigned short* __restrict__ Wq,
                 const float* __restrict__ wp,   unsigned short* __restrict__ Wp)
{
    const int gid = blockIdx.x * 256 + threadIdx.x;
    const int lane = gid & 63;
    if (gid < NA_TOT) {
        // x (fp32 [M][K]) -> A-fragments, HI-ONLY
        const int sub = gid >> 6;
        const int kt = sub % KT_D;
        const int mt = sub / KT_D;
        const float* s = x + (size_t)(mt*16 + (lane & 15)) * D_MODEL + kt*32 + (lane >> 4)*8;
        float4 v0 = *(const float4*)(s);
        float4 v1 = *(const float4*)(s + 4);
        float vv[8] = {v0.x, v0.y, v0.z, v0.w, v1.x, v1.y, v1.z, v1.w};
        union { unsigned short u[8]; bf16x8 v; } H;
        #pragma unroll
        for (int i = 0; i < 8; ++i) H.u[i] = f2bf(vv[i]);
        *(bf16x8*)(Xf + (size_t)sub * 512 + lane * 8) = H.v;
    } else {
        // weights (fp32 [K][N]) -> B-fragments, HI-ONLY
        const float* src;
        unsigned short* dst;
        int sub, ldN;
        if (gid < NA_TOT + NB1_TOT) {
            src = wq; dst = Wq; ldN = QKV_COLS; sub = (gid - NA_TOT) >> 6;
        } else if (gid < NA_TOT + NB1_TOT + NB2_TOT) {
            src = wp; dst = Wp; ldN = D_MODEL; sub = (gid - NA_TOT - NB1_TOT) >> 6;
        } else {
            return;
        }
        const int kt = sub % KT_D;
        const int nt = sub / KT_D;
        const int n  = nt*16 + (lane & 15);
        const int k0 = kt*32 + (lane >> 4)*8;
        const float* s = src + (size_t)k0 * ldN + n;
        union { unsigned short u[8]; bf16x8 v; } H;
        #pragma unroll
        for (int i = 0; i < 8; ++i) H.u[i] = f2bf(s[(size_t)i * ldN]);
        *(bf16x8*)(dst + (size_t)sub * 512 + lane * 8) = H.v;
    }
}

// ---- fragment GEMM, pure bf16, 3-buffer 1-barrier counted-vmcnt pipeline -----
// 3-unrolled steady loop: every LDS buffer index compile-time. Schedule per kt:
// [vmcnt(CPW) — kt's chunks landed (issued 2 iters ago); s_barrier; stage kt+2;
// ds_read buf kt%3; setprio(1) MFMA setprio(0)].
// MODE 0: 8 waves (2x4), 128x128 tile, 48KB LDS; __launch_bounds__(512,6):
//         76 unified regs (44 arch + 32 acc) <= 85 cap -> 3 blocks/CU (24
//         waves), up from 2 — the 2-block residency left ~33% of each kt slot
//         as uncovered latency. Scatters Q/K/V hi-only frags.
// MODE 1: 4 waves (2x2), 128x64 tile, 36KB LDS (LDS-capped at 4 blocks); fp32.
// 1-D grid, XCD swizzle: mb=(bid&7)*8+((bid>>3)&7), nb=bid>>6.
template<int MODE>
__global__ __launch_bounds__(MODE == 0 ? 512 : 256, MODE == 0 ? 6 : 4)
void gemm_frag(const unsigned short* __restrict__ Af,
               const unsigned short* __restrict__ Bf,
               const float* __restrict__ bias,
               float* __restrict__ outF,
               unsigned short* __restrict__ outQ,
               unsigned short* __restrict__ outK,
               unsigned short* __restrict__ outV)
{
    constexpr int NW     = (MODE == 0) ? 8 : 4;     // waves per block
    constexpr int NSUB_N = (MODE == 0) ? 8 : 4;     // B subtiles per block
    constexpr int ACH    = 8;                       // A hi 1KB-chunks per kt
    constexpr int NCH    = ACH + NSUB_N;            // chunks per kt (16 / 12)
    constexpr int CPW    = NCH / NW;                // chunks per wave (2 / 3)
    __shared__ unsigned short sm[3][NCH * 512];
    const int t = threadIdx.x, lane = t & 63, wid = t >> 6;
    const int wr = (MODE == 0) ? (wid >> 2) : (wid >> 1);
    const int wc = (MODE == 0) ? (wid & 3)  : (wid & 1);
    const int bid = blockIdx.x;
    const int mb = (bid & 7) * 8 + ((bid >> 3) & 7);
    const int nb = bid >> 6;

    f32x4 acc[4][2] = {};

    // stage K-step ktv into buffer Lb (CPW chunks per wave)
    auto stageTo = [&](unsigned short* Lb, int ktv) {
        #pragma unroll
        for (int i = 0; i < CPW; ++i) {
            const int c = wid * CPW + i;
            const unsigned short* g;
            if (c < ACH) {                     // A hi subtile c
                g = Af + ((size_t)(mb*8 + c)*KT_D + ktv)*512 + lane*8;
            } else {                           // B hi subtile j
                const int j = c - ACH;
                g = Bf + ((size_t)(nb*NSUB_N + j)*KT_D + ktv)*512 + lane*8;
            }
            gload16(g, (const char*)Lb + (size_t)c*1024);
        }
    };
    auto waitCPW = [&] {
        if (MODE == 0) asm volatile("s_waitcnt vmcnt(2)" ::: "memory");
        else           asm volatile("s_waitcnt vmcnt(3)" ::: "memory");
    };
    auto compute = [&](const unsigned short* Lb) {
        bf16x8 bh[2];
        #pragma unroll
        for (int n = 0; n < 2; ++n)
            bh[n] = *(const bf16x8*)(Lb + (ACH + wc*2 + n)*512 + lane*8);
        bf16x8 ah[4];
        #pragma unroll
        for (int m = 0; m < 4; ++m)
            ah[m] = *(const bf16x8*)(Lb + (wr*4 + m)*512 + lane*8);
        __builtin_amdgcn_s_setprio(1);
        #pragma unroll
        for (int m = 0; m < 4; ++m)
            #pragma unroll
            for (int n = 0; n < 2; ++n)
                acc[m][n] = MFMA16(ah[m], bh[n], acc[m][n]);
        __builtin_amdgcn_s_setprio(0);
    };

    stageTo(&sm[0][0], 0);
    stageTo(&sm[1][0], 1);

    // steady: buffer indices compile-time; KT_D%3==0
    for (int ktb = 0; ktb < KT_D - 3; ktb += 3) {
        waitCPW(); __builtin_amdgcn_s_barrier();
        stageTo(&sm[2][0], ktb + 2);  compute(&sm[0][0]);
        waitCPW(); __builtin_amdgcn_s_barrier();
        stageTo(&sm[0][0], ktb + 3);  compute(&sm[1][0]);
        waitCPW(); __builtin_amdgcn_s_barrier();
        stageTo(&sm[1][0], ktb + 4);  compute(&sm[2][0]);
    }
    // tail: kt = KT_D-3 (stages KT_D-1), KT_D-2, KT_D-1 (bufs 0,1,2)
    waitCPW(); __builtin_amdgcn_s_barrier();
    stageTo(&sm[2][0], KT_D - 1);  compute(&sm[0][0]);
    waitCPW(); __builtin_amdgcn_s_barrier();
    compute(&sm[1][0]);
    asm volatile("s_waitcnt vmcnt(0)" ::: "memory");
    __builtin_amdgcn_s_barrier();
    compute(&sm[2][0]);

    const int rowW = mb*128 + wr*64;
    const int colW = nb*(NSUB_N*16) + wc*32;
    if (MODE == 1) {
        #pragma unroll
        for (int m = 0; m < 4; ++m)
            #pragma unroll
            for (int n = 0; n < 2; ++n) {
                const int col = colW + n*16 + (lane & 15);
                const float bv = bias[col];
                #pragma unroll
                for (int r = 0; r < 4; ++r) {
                    const int row = rowW + m*16 + (lane >> 4)*4 + r;
                    outF[(size_t)row * D_MODEL + col] = acc[m][n][r] + bv;
                }
            }
    } else {
        // wave-uniform (which, head): colW..colW+31 stays inside one head (64-wide)
        const int which = colW / D_MODEL;
        const int h     = (colW % D_MODEL) >> 6;
        #pragma unroll
        for (int m = 0; m < 4; ++m)
            #pragma unroll
            for (int n = 0; n < 2; ++n) {
                const int col = colW + n*16 + (lane & 15);
                const int d = col & 63;
                const float bv = bias[col];
                #pragma unroll
                for (int r = 0; r < 4; ++r) {
                    const int row = rowW + m*16 + (lane >> 4)*4 + r;
                    const int b = row >> 10, sq = row & 1023;
                    float val = acc[m][n][r] + bv;
                    if (which <= 1) {                    // Q (scaled) / K: hi-only A-frag
                        if (which == 0) val *= QSCALE;
                        const int sub = (sq >> 4)*2 + (d >> 5);
                        const int lp  = (sq & 15) + (((d & 31) >> 3) << 4);
                        unsigned short* dst = (which == 0) ? outQ : outK;
                        dst[(size_t)(b*NHEADS + h)*65536
                            + (size_t)sub*512 + lp*8 + (d & 7)] = f2bf(val);
                    } else {                             // V: hi-only B-frag
                        const int sub = (d >> 4)*32 + (sq >> 5);
                        const int lp  = (d & 15) + (((sq & 31) >> 3) << 4);
                        outV[(size_t)(b*NHEADS + h)*65536
                             + (size_t)sub*512 + lp*8 + (sq & 7)] = f2bf(val);
                    }
                }
            }
    }
}

// ---- flash attention: 8 waves x 16 q-rows, SWAPPED QK^T (S^T = K x Q) --------
// Swapped operands put P row-local: thread owns q = lane&15 and k = 16*jn +
// qrow0 + r — 4 consecutive k per jn -> P store is 4 ds_write_b64/jt, scalar
// m/alpha, 2-shuffle row reduce. dbuf K/V staging; Q,K,V hi-only; PV hi-only;
// MFMA-ones rowsum (trunc-P); defer-max THR=8; exp2 domain; setprio clusters.
__global__ __launch_bounds__(512, 6)
void attn_frag(const unsigned short* __restrict__ Qf,
               const unsigned short* __restrict__ Kf,
               const unsigned short* __restrict__ Vf,
               unsigned short* __restrict__ Cf)
{
    __shared__ unsigned short Ksm[2][8 * 512];   // dbuf: 4 jn x 2 kt hi subtiles
    __shared__ unsigned short Vsm[2][8 * 512];   // dbuf: 4 dt x 2 kt2 hi subtiles
    __shared__ unsigned short Psm[8 * 1024];     // per-wave P: 2 subtiles x 512 bf16

    const int t = threadIdx.x, lane = t & 63, wid = t >> 6;   // wid 0..7
    // XCD swizzle: all 8 q-blocks of one (b,h) land on the same XCD
    const int bid = blockIdx.x;
    const int qb  = (bid >> 3) & 7;
    const int bh  = (bid & 7) * 12 + (bid >> 6);
    const int mt0 = qb*8 + wid;                // wave's q-subtile (of 64)
    const size_t kBase = (size_t)bh * 65536;   // Q/K/V all 65536-stride

    const int qrow0 = (lane >> 4) * 4;         // 0,4,8,12
    const int slot0 = ((lane >> 4) & 1) * 4;   // 0/4: k-slot base for P store

    // stage K/V hi subtiles of kv-tile jt into buffer b (2 chunks per wave)
    auto stage = [&](int b, int jt) {
        #pragma unroll
        for (int i = 0; i < 2; ++i) {
            const int ch = wid*2 + i;
            if (ch < 8) {
                const unsigned short* gk = Kf + kBase + (size_t)(jt*8 + ch)*512;
                gload16(gk + lane*8, (const char*)&Ksm[b][0] + (size_t)ch*1024);
            } else {
                const int cv = ch - 8;                 // dt = cv>>1, kt2 = cv&1
                const unsigned short* gv = Vf + kBase
                    + (size_t)((cv >> 1)*32 + jt*2 + (cv & 1))*512;
                gload16(gv + lane*8, (const char*)&Vsm[b][0] + (size_t)cv*1024);
            }
        }
    };

    stage(0, 0);                               // prologue: tile 0 into buf 0

    // Q hi fragments in registers (already scaled by QSCALE); overlap prologue.
    bf16x8 qh[2];
    #pragma unroll
    for (int kt = 0; kt < 2; ++kt)
        qh[kt] = *(const bf16x8*)(Qf + kBase + ((size_t)mt0*2 + kt)*512 + lane*8);

    // ones B-frag for the MFMA rowsum
    bf16x8 ones;
    #pragma unroll
    for (int i = 0; i < 8; ++i) ones[i] = (short)0x3F80;

    f32x4 out[4] = {};
    f32x4 lacc = {};
    float m_run = -INFINITY;                   // scalar: this thread's q row

    unsigned short* Pw = Psm + wid * 1024;

    __syncthreads();                           // prologue stage complete

    for (int jt = 0; jt < 16; ++jt) {
        const int cur = jt & 1;
        if (jt + 1 < 16) stage(cur ^ 1, jt + 1);   // prefetch next tile (hidden)

        // S^T = K Q (swapped): s[jn][r] = S[q=lane&15][k=16*jn+qrow0+r]
        f32x4 s[4] = {};
        __builtin_amdgcn_s_setprio(1);
        #pragma unroll
        for (int jn = 0; jn < 4; ++jn)
            #pragma unroll
            for (int kt = 0; kt < 2; ++kt) {
                const bf16x8 kh = *(const bf16x8*)(&Ksm[cur][0] + (jn*2 + kt)*512 + lane*8);
                s[jn] = MFMA16(kh, qh[kt], s[jn]);
            }
        __builtin_amdgcn_s_setprio(0);

        // defer-max: in-lane max over this q's 16 k-values
        float mymax = s[0][0];
        #pragma unroll
        for (int jn = 0; jn < 4; ++jn)
            #pragma unroll
            for (int r = 0; r < 4; ++r)
                mymax = fmaxf(mymax, s[jn][r]);
        if (!__all(mymax <= m_run + 8.0f)) {
            float v = mymax;
            v = fmaxf(v, __shfl_xor(v, 16));
            v = fmaxf(v, __shfl_xor(v, 32));
            const float mn = fmaxf(m_run, v);
            const float al = exp2_fast(m_run - mn);
            m_run = mn;
            #pragma unroll
            for (int r = 0; r < 4; ++r) {
                const float alf = __shfl(al, qrow0 + r);   // alpha of out-row q'
                #pragma unroll
                for (int dt = 0; dt < 4; ++dt)
                    out[dt][r] *= alf;
                lacc[r] *= alf;
            }
        }

        // P = exp2(s - m): 4 consecutive k per jn -> pack + ds_write_b64
        #pragma unroll
        for (int jn = 0; jn < 4; ++jn) {
            const unsigned b0 = __float_as_uint(exp2_fast(s[jn][0] - m_run));
            const unsigned b1 = __float_as_uint(exp2_fast(s[jn][1] - m_run));
            const unsigned b2 = __float_as_uint(exp2_fast(s[jn][2] - m_run));
            const unsigned b3 = __float_as_uint(exp2_fast(s[jn][3] - m_run));
            const unsigned u0 = (b0 >> 16) | (b1 & 0xFFFF0000u);
            const unsigned u1 = (b2 >> 16) | (b3 & 0xFFFF0000u);
            const int hi2 = ((jn & 1) << 1) + (lane >> 5);
            const int lp  = (lane & 15) + (hi2 << 4);
            const int idx = (((lp << 3) | slot0) ^ (lp & 0x18));
            *(uint2*)&Pw[(jn >> 1)*512 + idx] = make_uint2(u0, u1);
        }

        // PV + MFMA rowsum: read P back as bf16x8 A-frags (wave-local)
        const int rdswz = (lane*8) ^ (lane & 0x18);
        __builtin_amdgcn_s_setprio(1);
        #pragma unroll
        for (int kt2 = 0; kt2 < 2; ++kt2) {
            const bf16x8 pa = *(const bf16x8*)(Pw + kt2*512 + rdswz);
            #pragma unroll
            for (int dt = 0; dt < 4; ++dt) {
                const bf16x8 vh = *(const bf16x8*)(&Vsm[cur][0] + (dt*2 + kt2)*512 + lane*8);
                out[dt] = MFMA16(pa, vh, out[dt]);
            }
            lacc = MFMA16(pa, ones, lacc);
        }
        __builtin_amdgcn_s_setprio(0);

        __syncthreads();   // next tile staged by ALL waves; this tile's reads done
    }

    // epilogue: ctx / l -> proj-GEMM A-fragments, HI-ONLY
    const int b = bh / NHEADS, h = bh % NHEADS;
    #pragma unroll
    for (int r = 0; r < 4; ++r) {
        const float inv = 1.0f / lacc[r];
        const int sq = mt0*16 + qrow0 + r;
        const int mrow = b*SEQ + sq;
        #pragma unroll
        for (int dt = 0; dt < 4; ++dt) {
            const int c = h*64 + dt*16 + (lane & 15);
            const float val = out[dt][r] * inv;
            Cf[((size_t)(mrow >> 4)*KT_D + (c >> 5))*512
               + ((mrow & 15) + (((c & 31) >> 3) << 4))*8 + (c & 7)] = f2bf(val);
        }
    }
}

// ---------------------------------------------------------------------------
extern "C" void kernel_launch(void* const* d_in, const int* in_sizes, int n_in,
                              void* d_out, int out_size, void* d_ws, size_t ws_size,
                              hipStream_t stream)
{
    const float* x      = (const float*)d_in[0];
    const float* w_qkv  = (const float*)d_in[1];
    const float* b_qkv  = (const float*)d_in[2];
    const float* w_proj = (const float*)d_in[3];
    const float* b_proj = (const float*)d_in[4];
    float* out = (float*)d_out;

    unsigned short* ws = (unsigned short*)d_ws;
    unsigned short* Xf = ws;                    // 12288 sub * 512    =  6,291,456
    unsigned short* Wq = Xf + 6291456;          // 3456 sub * 512     =  1,769,472
    unsigned short* Wp = Wq + 1769472;          // 1152 sub * 512     =    589,824
    unsigned short* Qf = Wp + 589824;           // 96 * 65536         =  6,291,456
    unsigned short* Kf = Qf + 6291456;          // 96 * 65536         =  6,291,456
    unsigned short* Vf = Kf + 6291456;          // 96 * 65536         =  6,291,456
    unsigned short* Cf = Vf + 6291456;          // 12288 sub * 512    =  6,291,456
    // total ~33.8M ushorts = ~64 MB of d_ws

    // fused converts: (786432 + 221184 + 73728) threads = 4224 blocks
    convert_all<<<dim3(4224), 256, 0, stream>>>(x, Xf, w_qkv, Wq, w_proj, Wp);

    // gemm0: 128x128 tiles -> grid 64 x 18 = 1152 (mb-swizzled, nb = bid>>6)
    gemm_frag<0><<<dim3(1152), 512, 0, stream>>>(Xf, Wq, b_qkv, nullptr, Qf, Kf, Vf);
    attn_frag<<<dim3(768), 512, 0, stream>>>(Qf, Kf, Vf, Cf);
    // gemm1: 128x64 tiles -> grid 64 x 12 = 768
    gemm_frag<1><<<dim3(768), 256, 0, stream>>>(Cf, Wp, b_proj, out,
                                                nullptr, nullptr, nullptr);
}